// Round 2
// 278.544 us; speedup vs baseline: 1.0330x; 1.0330x over previous
//
#include <hip/hip_runtime.h>
#include <math.h>

// out = softmax(Q @ M^T / 0.02) @ M ; B=8, L=2048, D=1024, fp32.
// Round 4 (resubmit — previous bench died to a container failure, not the kernel):
//  - convert_k rewritten with LDS transpose: both global sides fully
//    coalesced (was: 4KB-strided reads -> TA-bound at ~1.4 TB/s).
//  - attn_main QK^T loop software-pipelined: depth-1 ping-pong prefetch of
//    the 6 operand fragments per dblk while 8 MFMAs run (was: batch 24
//    loads, drain vmcnt, compute -> 19% MfmaUtil at 2 waves/SIMD).
// Exact fp32 refinement epilogue unchanged. Fallback = round-2 kernel.

typedef __bf16 bf16x8 __attribute__((ext_vector_type(8)));
typedef float  f32x4  __attribute__((ext_vector_type(4)));
typedef float  f32x16 __attribute__((ext_vector_type(16)));

constexpr int   B_    = 8;
constexpr int   L_    = 2048;
constexpr int   D_    = 1024;
constexpr float SCALE  = 50.0f;   // 1/0.02
constexpr float MARGIN = 1.2f;    // dot units; 0.6 needed + 0.6 bf16-err guard
constexpr int   BQ    = 64;       // q rows per block
constexpr int   RCAP  = 64;       // per-row survivor capacity

// ws: bf16 T[2][8][64][2048][16] ; t=0 Q, t=1 M. (dblk,r)-granule = 16 elems.
constexpr size_t WS_T_ELEMS = (size_t)8 * 64 * 2048 * 16;   // 16,777,216
constexpr size_t WS_NEED    = 2 * WS_T_ELEMS * 2;           // 67,108,864 B

static __device__ __forceinline__ unsigned short f2bf(float x) {
    unsigned u = __builtin_bit_cast(unsigned, x);
    u += 0x7FFFu + ((u >> 16) & 1u);   // RNE
    return (unsigned short)(u >> 16);
}

// ---------------- conversion: fp32 [b][r][d] -> bf16 tiled [b][dblk][r][16] --
// 64r x 64d tile per block; coalesced reads, LDS transpose, coalesced writes.
__global__ __launch_bounds__(256) void convert_k(
    const float* __restrict__ Q, const float* __restrict__ M,
    __bf16* __restrict__ ws)
{
    __shared__ unsigned short lds[64][72];   // 64 cols + 8 pad (keeps 16B align)

    const int t   = blockIdx.y;
    const int x   = blockIdx.x;        // 4096 = d0(16) | r0(32) | b(8)
    const int d0  = x & 15;            // * 64 cols
    const int r0  = (x >> 4) & 31;     // * 64 rows
    const int b   = x >> 9;
    const int tid = threadIdx.x;

    const float* src = (t ? M : Q)
                     + ((size_t)b * L_ + (size_t)r0 * 64) * D_ + d0 * 64;

    // phase 1: read 64x64 fp32 (coalesced 256B row segments), convert to LDS
    {
        const int row = tid >> 4;      // 0..15
        const int c4  = tid & 15;      // float4 within row
        #pragma unroll
        for (int a = 0; a < 4; ++a) {
            const int rr = a * 16 + row;
            float4 v = *(const float4*)(src + (size_t)rr * D_ + c4 * 4);
            union { unsigned short h[4]; uint2 u; } o;
            o.h[0] = f2bf(v.x); o.h[1] = f2bf(v.y);
            o.h[2] = f2bf(v.z); o.h[3] = f2bf(v.w);
            *(uint2*)&lds[rr][c4 * 4] = o.u;
        }
    }
    __syncthreads();

    // phase 2: write tiled granules (dblk, r, 16); lanes consecutive in r
    {
        const int r    = tid & 63;
        const int d4   = tid >> 6;     // 0..3
        const int dblk = d0 * 4 + d4;
        __bf16* dst = ws + ((size_t)t * 8 + b) * (64ull * 2048 * 16)
                         + ((size_t)dblk * 2048 + (size_t)r0 * 64 + r) * 16;
        uint4 u0 = *(const uint4*)&lds[r][d4 * 16];
        uint4 u1 = *(const uint4*)&lds[r][d4 * 16 + 8];
        ((uint4*)dst)[0] = u0;
        ((uint4*)dst)[1] = u1;
    }
}

// ---------------- main kernel ------------------------------------------------
__global__ __launch_bounds__(512, 2) void attn_main(
    const float* __restrict__ Q, const float* __restrict__ M,
    const __bf16* __restrict__ ws, float* __restrict__ Out)
{
    __shared__ float wmax[8][BQ];
    __shared__ float rm_s[BQ], thr_s[BQ];
    __shared__ int   rowcnt[BQ];
    __shared__ int   rowlist[BQ][RCAP];   // 16 KB
    __shared__ float rowval[BQ][RCAP];    // 16 KB: approx at push, exact after E1

    const int b    = blockIdx.x & 7;      // batch per XCD for L2 locality
    const int qt   = blockIdx.x >> 3;
    const int q0   = qt * BQ;
    const int tid  = threadIdx.x;
    const int w    = tid >> 6;
    const int lane = tid & 63;
    const int ln31 = lane & 31;
    const int h2   = lane >> 5;

    const __bf16* qws = ws + (size_t)b * (64ull * 2048 * 16);
    const __bf16* mws = ws + ((size_t)8 + b) * (64ull * 2048 * 16);
    const float*  Qb  = Q + ((size_t)b * L_ + q0) * D_;
    const float*  Mb  = M + (size_t)b * L_ * D_;

    if (tid < BQ) { rm_s[tid] = -INFINITY; rowcnt[tid] = 0; }
    __syncthreads();

    constexpr size_t DSTR = 2048 * 16;    // elems per dblk step (64 KB)

    #pragma unroll 1
    for (int kt = 0; kt < 2; ++kt) {
        const int nb = kt * 1024 + w * 128;   // this wave's kv base

        f32x16 acc[2][4];
        #pragma unroll
        for (int i = 0; i < 2; ++i)
            #pragma unroll
            for (int j = 0; j < 4; ++j)
                #pragma unroll
                for (int e = 0; e < 16; ++e) acc[i][j][e] = 0.f;

        const __bf16* qpb = qws + ((size_t)(q0 + ln31)) * 16 + h2 * 8;
        const __bf16* mpb = mws + ((size_t)(nb + ln31)) * 16 + h2 * 8;

        // ping-pong fragment sets (named regs: no runtime indexing)
        bf16x8 aA0, aA1, bA0, bA1, bA2, bA3;
        bf16x8 aB0, aB1, bB0, bB1, bB2, bB3;

#define LOADSET(s, dblk_) do {                                             \
        const __bf16* qp_##s = qpb + (size_t)(dblk_) * DSTR;               \
        const __bf16* mp_##s = mpb + (size_t)(dblk_) * DSTR;               \
        a##s##0 = *(const bf16x8*)(qp_##s);                                \
        a##s##1 = *(const bf16x8*)(qp_##s + 32 * 16);                      \
        b##s##0 = *(const bf16x8*)(mp_##s);                                \
        b##s##1 = *(const bf16x8*)(mp_##s + 32 * 16);                      \
        b##s##2 = *(const bf16x8*)(mp_##s + 64 * 16);                      \
        b##s##3 = *(const bf16x8*)(mp_##s + 96 * 16);                      \
    } while (0)

#define MFMASET(s) do {                                                    \
        acc[0][0] = __builtin_amdgcn_mfma_f32_32x32x16_bf16(               \
            a##s##0, b##s##0, acc[0][0], 0, 0, 0);                         \
        acc[0][1] = __builtin_amdgcn_mfma_f32_32x32x16_bf16(               \
            a##s##0, b##s##1, acc[0][1], 0, 0, 0);                         \
        acc[0][2] = __builtin_amdgcn_mfma_f32_32x32x16_bf16(               \
            a##s##0, b##s##2, acc[0][2], 0, 0, 0);                         \
        acc[0][3] = __builtin_amdgcn_mfma_f32_32x32x16_bf16(               \
            a##s##0, b##s##3, acc[0][3], 0, 0, 0);                         \
        acc[1][0] = __builtin_amdgcn_mfma_f32_32x32x16_bf16(               \
            a##s##1, b##s##0, acc[1][0], 0, 0, 0);                         \
        acc[1][1] = __builtin_amdgcn_mfma_f32_32x32x16_bf16(               \
            a##s##1, b##s##1, acc[1][1], 0, 0, 0);                         \
        acc[1][2] = __builtin_amdgcn_mfma_f32_32x32x16_bf16(               \
            a##s##1, b##s##2, acc[1][2], 0, 0, 0);                         \
        acc[1][3] = __builtin_amdgcn_mfma_f32_32x32x16_bf16(               \
            a##s##1, b##s##3, acc[1][3], 0, 0, 0);                         \
    } while (0)

        LOADSET(A, 0);
        #pragma unroll 1
        for (int d = 0; d < 62; d += 2) {
            LOADSET(B, d + 1);     // prefetch next dblk while A computes
            MFMASET(A);
            LOADSET(A, d + 2);
            MFMASET(B);
        }
        LOADSET(B, 63);
        MFMASET(A);                // dblk 62
        MFMASET(B);                // dblk 63

#undef LOADSET
#undef MFMASET

        // ---- block-wide running rowmax ----
        float lm[2][16];
        #pragma unroll
        for (int i = 0; i < 2; ++i)
            #pragma unroll
            for (int g = 0; g < 16; ++g)
                lm[i][g] = fmaxf(fmaxf(acc[i][0][g], acc[i][1][g]),
                                 fmaxf(acc[i][2][g], acc[i][3][g]));
        #pragma unroll
        for (int off = 1; off <= 16; off <<= 1)
            #pragma unroll
            for (int i = 0; i < 2; ++i)
                #pragma unroll
                for (int g = 0; g < 16; ++g)
                    lm[i][g] = fmaxf(lm[i][g], __shfl_xor(lm[i][g], off, 64));
        if (ln31 == 0) {
            #pragma unroll
            for (int i = 0; i < 2; ++i)
                #pragma unroll
                for (int g = 0; g < 16; ++g)
                    wmax[w][i * 32 + (g & 3) + 8 * (g >> 2) + 4 * h2] = lm[i][g];
        }
        __syncthreads();
        if (tid < BQ) {
            float m = wmax[0][tid];
            #pragma unroll
            for (int ww = 1; ww < 8; ++ww) m = fmaxf(m, wmax[ww][tid]);
            m = fmaxf(m, rm_s[tid]);
            rm_s[tid] = m;
            thr_s[tid] = m - MARGIN;
        }
        __syncthreads();

        // ---- survivor push ----
        #pragma unroll
        for (int i = 0; i < 2; ++i)
            #pragma unroll
            for (int g = 0; g < 16; ++g) {
                const int rl = i * 32 + (g & 3) + 8 * (g >> 2) + 4 * h2;
                const float thr = thr_s[rl];
                #pragma unroll
                for (int j = 0; j < 4; ++j)
                    if (acc[i][j][g] > thr) {
                        int t = atomicAdd(&rowcnt[rl], 1);
                        if (t < RCAP) {
                            rowlist[rl][t] = nb + j * 32 + ln31;
                            rowval[rl][t]  = acc[i][j][g];
                        }
                    }
            }
    }
    __syncthreads();

    // ---- E1: refilter vs final max, exact fp32 dot for keepers ----
    #pragma unroll 1
    for (int r = w; r < BQ; r += 8) {
        const int c = min(rowcnt[r], RCAP);
        const float thrf = rm_s[r] - MARGIN;
        #pragma unroll 1
        for (int t = 0; t < c; ++t) {
            const float av = rowval[r][t];           // broadcast read
            if (av > thrf) {
                const int k = rowlist[r][t];
                const f32x4* qp = (const f32x4*)(Qb + (size_t)r * D_);
                const f32x4* mp = (const f32x4*)(Mb + (size_t)k * D_);
                float dot = 0.f;
                #pragma unroll
                for (int c4 = 0; c4 < 4; ++c4) {
                    f32x4 x = qp[lane + 64 * c4];
                    f32x4 y = mp[lane + 64 * c4];
                    dot += x[0]*y[0] + x[1]*y[1] + x[2]*y[2] + x[3]*y[3];
                }
                #pragma unroll
                for (int off = 32; off >= 1; off >>= 1)
                    dot += __shfl_xor(dot, off, 64);
                if (lane == 0) rowval[r][t] = dot;
            } else if (lane == 0) rowval[r][t] = -1e30f;
        }
    }
    __syncthreads();

    // ---- E2: exact softmax + PV per row ----
    #pragma unroll 1
    for (int r = w; r < BQ; r += 8) {
        const int c = min(rowcnt[r], RCAP);
        float mstar = -1e30f;
        for (int t = 0; t < c; ++t) mstar = fmaxf(mstar, rowval[r][t]);
        float denom = 0.f;
        f32x4 o[4];
        #pragma unroll
        for (int c4 = 0; c4 < 4; ++c4) o[c4] = (f32x4){0.f, 0.f, 0.f, 0.f};
        #pragma unroll 1
        for (int t = 0; t < c; ++t) {
            const float wgt = __expf(SCALE * (rowval[r][t] - mstar));
            if (wgt > 1e-22f) {
                denom += wgt;
                const f32x4* mp = (const f32x4*)(Mb + (size_t)rowlist[r][t] * D_);
                #pragma unroll
                for (int c4 = 0; c4 < 4; ++c4)
                    o[c4] += mp[lane + 64 * c4] * wgt;
            }
        }
        const float inv = 1.f / denom;
        f32x4* op = (f32x4*)(Out + ((size_t)b * L_ + q0 + r) * D_);
        #pragma unroll
        for (int c4 = 0; c4 < 4; ++c4) op[lane + 64 * c4] = o[c4] * inv;
    }
}

// ---------------- round-2 fallback (used only if ws too small) ---------------
constexpr int   FB_BKV  = 256;
constexpr int   FB_NKT  = L_ / FB_BKV;
constexpr int   FB_BD   = 32;
constexpr int   FB_NDC  = D_ / FB_BD;
constexpr int   FB_STR  = FB_BD + 8;
constexpr int   FB_CAP  = 2048;

__global__ __launch_bounds__(256) void attn_fb(
    const float* __restrict__ Q, const float* __restrict__ M,
    float* __restrict__ Out)
{
    __shared__ __bf16 qs[BQ * FB_STR];
    __shared__ __bf16 ms[FB_BKV * FB_STR];
    __shared__ float  wmax[4][BQ];
    __shared__ float  rowmax_s[BQ];
    __shared__ int    cnt_s;
    __shared__ int    list_s[FB_CAP];
    __shared__ float  elist_s[FB_CAP];

    const int b    = blockIdx.x & 7;
    const int qt   = blockIdx.x >> 3;
    const int q0   = qt * BQ;
    const int tid  = threadIdx.x;
    const int w    = tid >> 6;
    const int lane = tid & 63;
    const int ln15 = lane & 15;
    const int quad = lane >> 4;

    const float* Qb = Q + ((size_t)b * L_ + q0) * D_;
    const float* Mb = M + (size_t)b * L_ * D_;

    float rm[4][4];
    #pragma unroll
    for (int i = 0; i < 4; ++i)
        #pragma unroll
        for (int r = 0; r < 4; ++r) rm[i][r] = -INFINITY;

    #pragma unroll 1
    for (int pass = 0; pass < 2; ++pass) {
        #pragma unroll 1
        for (int kt = 0; kt < FB_NKT; ++kt) {
            f32x4 acc[4][4];
            #pragma unroll
            for (int i = 0; i < 4; ++i)
                #pragma unroll
                for (int j = 0; j < 4; ++j)
                    acc[i][j] = (f32x4){0.f, 0.f, 0.f, 0.f};
            const float* Mt = Mb + (size_t)(kt * FB_BKV) * D_;
            #pragma unroll 1
            for (int dc = 0; dc < FB_NDC; ++dc) {
                const int d0 = dc * FB_BD;
                __syncthreads();
                #pragma unroll
                for (int i = 0; i < 2; ++i) {
                    int f4 = tid + i * 256, row = f4 >> 3, c = f4 & 7;
                    float4 v = *(const float4*)(Qb + row * D_ + d0 + c * 4);
                    union { unsigned short h[4]; uint2 u; } t;
                    t.h[0] = f2bf(v.x); t.h[1] = f2bf(v.y);
                    t.h[2] = f2bf(v.z); t.h[3] = f2bf(v.w);
                    *(uint2*)(qs + row * FB_STR + c * 4) = t.u;
                }
                #pragma unroll
                for (int i = 0; i < 8; ++i) {
                    int f4 = tid + i * 256, row = f4 >> 3, c = f4 & 7;
                    float4 v = *(const float4*)(Mt + row * D_ + d0 + c * 4);
                    union { unsigned short h[4]; uint2 u; } t;
                    t.h[0] = f2bf(v.x); t.h[1] = f2bf(v.y);
                    t.h[2] = f2bf(v.z); t.h[3] = f2bf(v.w);
                    *(uint2*)(ms + row * FB_STR + c * 4) = t.u;
                }
                __syncthreads();
                bf16x8 afr[4], bfr[4];
                #pragma unroll
                for (int i = 0; i < 4; ++i)
                    afr[i] = *(const bf16x8*)(qs + (i * 16 + ln15) * FB_STR + quad * 8);
                #pragma unroll
                for (int j = 0; j < 4; ++j)
                    bfr[j] = *(const bf16x8*)(ms + (w * 64 + j * 16 + ln15) * FB_STR + quad * 8);
                #pragma unroll
                for (int i = 0; i < 4; ++i)
                    #pragma unroll
                    for (int j = 0; j < 4; ++j)
                        acc[i][j] = __builtin_amdgcn_mfma_f32_16x16x32_bf16(
                            afr[i], bfr[j], acc[i][j], 0, 0, 0);
            }
            if (pass == 0) {
                #pragma unroll
                for (int i = 0; i < 4; ++i)
                    #pragma unroll
                    for (int r = 0; r < 4; ++r) {
                        float m0 = fmaxf(fmaxf(acc[i][0][r], acc[i][1][r]),
                                         fmaxf(acc[i][2][r], acc[i][3][r]));
                        rm[i][r] = fmaxf(rm[i][r], m0);
                    }
            } else {
                #pragma unroll
                for (int i = 0; i < 4; ++i)
                    #pragma unroll
                    for (int j = 0; j < 4; ++j)
                        #pragma unroll
                        for (int r = 0; r < 4; ++r)
                            if (acc[i][j][r] > rm[i][r]) {
                                int idx = atomicAdd(&cnt_s, 1);
                                if (idx < FB_CAP)
                                    list_s[idx] = ((i * 16 + quad * 4 + r) << 16) |
                                                  (kt * FB_BKV + w * 64 + j * 16 + ln15);
                            }
            }
        }
        if (pass == 0) {
            #pragma unroll
            for (int i = 0; i < 4; ++i)
                #pragma unroll
                for (int r = 0; r < 4; ++r) {
                    float v = rm[i][r];
                    v = fmaxf(v, __shfl_xor(v, 1, 64));
                    v = fmaxf(v, __shfl_xor(v, 2, 64));
                    v = fmaxf(v, __shfl_xor(v, 4, 64));
                    v = fmaxf(v, __shfl_xor(v, 8, 64));
                    rm[i][r] = v;
                }
            if (ln15 == 0) {
                #pragma unroll
                for (int i = 0; i < 4; ++i)
                    #pragma unroll
                    for (int r = 0; r < 4; ++r)
                        wmax[w][i * 16 + quad * 4 + r] = rm[i][r];
            }
            __syncthreads();
            if (tid < BQ)
                rowmax_s[tid] = fmaxf(fmaxf(wmax[0][tid], wmax[1][tid]),
                                      fmaxf(wmax[2][tid], wmax[3][tid]));
            if (tid == 0) cnt_s = 0;
            __syncthreads();
            #pragma unroll
            for (int i = 0; i < 4; ++i)
                #pragma unroll
                for (int r = 0; r < 4; ++r)
                    rm[i][r] = rowmax_s[i * 16 + quad * 4 + r] - MARGIN;
        }
    }
    __syncthreads();
    const int n = min(cnt_s, FB_CAP);
    #pragma unroll 1
    for (int s = w; s < n; s += 4) {
        int e = list_s[s];
        int q = e >> 16, k = e & 0xFFFF;
        const float4* qp = (const float4*)(Qb + q * D_);
        const float4* mp = (const float4*)(Mb + (size_t)k * D_);
        float dot = 0.f;
        #pragma unroll
        for (int c = 0; c < 4; ++c) {
            float4 x = qp[lane + 64 * c];
            float4 y = mp[lane + 64 * c];
            dot += x.x * y.x + x.y * y.y + x.z * y.z + x.w * y.w;
        }
        #pragma unroll
        for (int off = 32; off >= 1; off >>= 1)
            dot += __shfl_xor(dot, off, 64);
        if (lane == 0) elist_s[s] = dot;
    }
    __syncthreads();
    #pragma unroll 1
    for (int r = w; r < BQ; r += 4) {
        float mstar = -INFINITY;
        for (int s = 0; s < n; ++s)
            if ((list_s[s] >> 16) == r) mstar = fmaxf(mstar, elist_s[s]);
        float denom = 0.f;
        f32x4 o[4];
        #pragma unroll
        for (int c = 0; c < 4; ++c) o[c] = (f32x4){0.f, 0.f, 0.f, 0.f};
        for (int s = 0; s < n; ++s) {
            if ((list_s[s] >> 16) != r) continue;
            float wgt = __expf(SCALE * (elist_s[s] - mstar));
            denom += wgt;
            const f32x4* mp = (const f32x4*)(Mb + (size_t)(list_s[s] & 0xFFFF) * D_);
            #pragma unroll
            for (int c = 0; c < 4; ++c) o[c] += mp[lane + 64 * c] * wgt;
        }
        const float inv = 1.f / denom;
        f32x4* op = (f32x4*)(Out + ((size_t)b * L_ + q0 + r) * D_);
        #pragma unroll
        for (int c = 0; c < 4; ++c) op[lane + 64 * c] = o[c] * inv;
    }
}

extern "C" void kernel_launch(void* const* d_in, const int* in_sizes, int n_in,
                              void* d_out, int out_size, void* d_ws, size_t ws_size,
                              hipStream_t stream)
{
    const float* Q = (const float*)d_in[0];
    const float* M = (const float*)d_in[1];
    float* Out = (float*)d_out;

    if (ws_size >= WS_NEED) {
        convert_k<<<dim3(4096, 2), 256, 0, stream>>>(Q, M, (__bf16*)d_ws);
        attn_main<<<dim3(256), 512, 0, stream>>>(Q, M, (const __bf16*)d_ws, Out);
    } else {
        attn_fb<<<dim3(256), 256, 0, stream>>>(Q, M, Out);
    }
}